// Round 1
// baseline (43.905 us; speedup 1.0000x reference)
//
#include <hip/hip_runtime.h>

constexpr int NB = 32;
constexpr int NPAIR = NB * NB;          // 1024
constexpr int HSIZE = NPAIR + NB;       // 1056: pair hist + per-label counts
constexpr int DD = 96, HH = 96, WW = 96;
constexpr int NBATCH = 2;
constexpr int SD = HH * WW;             // 9216
constexpr int SH = WW;                  // 96
constexpr int NVOX = NBATCH * DD * HH * WW;  // 1769472

__global__ void zero_kernel(unsigned int* ws, int n) {
    int t = blockIdx.x * blockDim.x + threadIdx.x;
    if (t < n) ws[t] = 0u;
}

__global__ __launch_bounds__(256) void adj_kernel(const int* __restrict__ tgt,
                                                  unsigned int* __restrict__ ws,
                                                  int npart_mask) {
    __shared__ unsigned int hist[HSIZE];
    for (int k = threadIdx.x; k < HSIZE; k += 256) hist[k] = 0u;
    __syncthreads();

    const int stride = gridDim.x * 256;
    for (int v = blockIdx.x * 256 + threadIdx.x; v < NVOX; v += stride) {
        int w = v % WW;
        int r1 = v / WW;
        int h = r1 % HH;
        int d = (r1 / HH) % DD;   // n never crosses: d+1<DD guard blocks it

        unsigned int i = (unsigned int)tgt[v];
        unsigned int ib = i << 5;
        atomicAdd(&hist[NPAIR + i], 1u);   // center (diagonal) count

        bool wp = (w + 1 < WW), wm = (w > 0);
        bool hp = (h + 1 < HH), hm = (h > 0);
        bool dp = (d + 1 < DD);

        // offset (0,0,1)
        if (wp) atomicAdd(&hist[ib + tgt[v + 1]], 1u);
        // offsets (0,1,*)
        if (hp) {
            const int* r = tgt + v + SH;
            atomicAdd(&hist[ib + r[0]], 1u);
            if (wm) atomicAdd(&hist[ib + r[-1]], 1u);
            if (wp) atomicAdd(&hist[ib + r[1]], 1u);
        }
        // offsets (1,*,*)
        if (dp) {
            const int* r = tgt + v + SD;
            atomicAdd(&hist[ib + r[0]], 1u);
            if (wm) atomicAdd(&hist[ib + r[-1]], 1u);
            if (wp) atomicAdd(&hist[ib + r[1]], 1u);
            if (hm) {
                const int* r2 = r - SH;
                atomicAdd(&hist[ib + r2[0]], 1u);
                if (wm) atomicAdd(&hist[ib + r2[-1]], 1u);
                if (wp) atomicAdd(&hist[ib + r2[1]], 1u);
            }
            if (hp) {
                const int* r2 = r + SH;
                atomicAdd(&hist[ib + r2[0]], 1u);
                if (wm) atomicAdd(&hist[ib + r2[-1]], 1u);
                if (wp) atomicAdd(&hist[ib + r2[1]], 1u);
            }
        }
    }
    __syncthreads();

    unsigned int* part = ws + (unsigned)(blockIdx.x & npart_mask) * HSIZE;
    for (int k = threadIdx.x; k < HSIZE; k += 256) {
        unsigned int val = hist[k];
        if (val) atomicAdd(&part[k], val);
    }
}

__global__ void final_kernel(const unsigned int* __restrict__ ws,
                             float* __restrict__ out, int nparts) {
    int t = blockIdx.x * blockDim.x + threadIdx.x;
    if (t >= NPAIR) return;
    int i = t >> 5, j = t & 31;
    unsigned long long s = 0;
    for (int p = 0; p < nparts; ++p) {
        const unsigned int* h = ws + p * HSIZE;
        s += (unsigned long long)h[(i << 5) + j] + h[(j << 5) + i];
        if (i == j) s += h[NPAIR + i];
    }
    out[t] = (float)s;
}

extern "C" void kernel_launch(void* const* d_in, const int* in_sizes, int n_in,
                              void* d_out, int out_size, void* d_ws, size_t ws_size,
                              hipStream_t stream) {
    const int* tgt = (const int*)d_in[0];
    float* out = (float*)d_out;
    unsigned int* ws = (unsigned int*)d_ws;

    // largest power-of-2 partial-histogram count that fits in ws (cap 32)
    int nparts = 1;
    while (nparts * 2 <= 32 &&
           (size_t)(nparts * 2) * HSIZE * sizeof(unsigned int) <= ws_size)
        nparts *= 2;

    int zn = nparts * HSIZE;
    zero_kernel<<<(zn + 255) / 256, 256, 0, stream>>>(ws, zn);
    adj_kernel<<<1024, 256, 0, stream>>>(tgt, ws, nparts - 1);
    final_kernel<<<(NPAIR + 255) / 256, 256, 0, stream>>>(ws, out, nparts);
}

// Round 2
// 38.890 us; speedup vs baseline: 1.1290x; 1.1290x over previous
//
#include <hip/hip_runtime.h>

constexpr int NB = 32;
constexpr int NPAIR = NB * NB;          // 1024
constexpr int HSIZE = NPAIR + NB;       // 1056
constexpr int DD = 96, HH = 96, WW = 96;
constexpr int NBATCH = 2;
constexpr int SD = HH * WW;             // 9216
constexpr int SH = WW;                  // 96
constexpr int NVOX = NBATCH * DD * HH * WW;  // 1769472
constexpr int NCH = NVOX / 4;           // 442368 chunks of 4 voxels along W
constexpr int CW = WW / 4;              // 24 chunks per row
constexpr int NBLK = 864;               // 864*256*2 == NCH exactly

__global__ void zero_kernel(unsigned int* ws, int n) {
    int t = blockIdx.x * blockDim.x + threadIdx.x;
    if (t < n) ws[t] = 0u;
}

__global__ __launch_bounds__(256) void adj_kernel(const int* __restrict__ tgt,
                                                  unsigned int* __restrict__ ws,
                                                  int npart_mask) {
    __shared__ unsigned int hist[HSIZE];
    for (int k = threadIdx.x; k < HSIZE; k += 256) hist[k] = 0u;
    __syncthreads();

    const int stride = gridDim.x * 256;
    for (int c = blockIdx.x * 256 + threadIdx.x; c < NCH; c += stride) {
        int cw = c % CW;
        int r  = c / CW;            // global row id (n*96*96 + d*96 + h) flattened
        int h  = r % HH;
        int d  = (r / HH) % DD;
        int v0 = c * 4;

        const bool hp = (h + 1 < HH), hm = (h > 0), dp = (d + 1 < DD);
        const bool vL = (cw > 0), vR = (cw < CW - 1);

        int4 Cc = *(const int4*)(tgt + v0);       // 16B-aligned center chunk
        int ci[4] = {Cc.x, Cc.y, Cc.z, Cc.w};
        int cR = vR ? tgt[v0 + 4] : 0;            // center row w0+4

        // the 4 neighbor rows for the 13 lexicographically-positive offsets:
        // (0,+1,*), (+1,-1,*), (+1,0,*), (+1,+1,*); plus (0,0,+1) from center row
        bool rowv[4];
        rowv[0] = hp; rowv[1] = dp && hm; rowv[2] = dp; rowv[3] = dp && hp;
        const int roff[4] = {SH, SD - SH, SD, SD + SH};
        int a[4][6];   // columns w0-1 .. w0+4 of each row
#pragma unroll
        for (int q = 0; q < 4; q++) {
            if (rowv[q]) {
                const int* p = tgt + v0 + roff[q];
                int4 m = *(const int4*)p;         // aligned: v0,roff multiples of 4
                a[q][1] = m.x; a[q][2] = m.y; a[q][3] = m.z; a[q][4] = m.w;
                a[q][0] = vL ? p[-1] : 0;
                a[q][5] = vR ? p[4]  : 0;
            }
        }

#pragma unroll
        for (int e = 0; e < 4; e++) {
            unsigned int ib = ((unsigned int)ci[e]) << 5;
            atomicAdd(&hist[NPAIR + ci[e]], 1u);            // center count (diag)
            // offset (0,0,+1)
            if (e < 3)       atomicAdd(&hist[ib + ci[e + 1]], 1u);
            else if (vR)     atomicAdd(&hist[ib + cR], 1u);
#pragma unroll
            for (int q = 0; q < 4; q++) {
                if (rowv[q]) {
                    if (e > 0 || vL) atomicAdd(&hist[ib + a[q][e]], 1u);
                    atomicAdd(&hist[ib + a[q][e + 1]], 1u);
                    if (e < 3 || vR) atomicAdd(&hist[ib + a[q][e + 2]], 1u);
                }
            }
        }
    }
    __syncthreads();

    unsigned int* part = ws + (unsigned)(blockIdx.x & npart_mask) * HSIZE;
    for (int k = threadIdx.x; k < HSIZE; k += 256) {
        unsigned int val = hist[k];
        if (val) atomicAdd(&part[k], val);
    }
}

__global__ void final_kernel(const unsigned int* __restrict__ ws,
                             float* __restrict__ out, int nparts) {
    int t = blockIdx.x * blockDim.x + threadIdx.x;
    if (t >= NPAIR) return;
    int i = t >> 5, j = t & 31;
    int tT = (j << 5) | i;
    unsigned long long s = 0;
#pragma unroll 4
    for (int p = 0; p < nparts; ++p) {
        const unsigned int* h = ws + p * HSIZE;
        s += (unsigned long long)h[t] + h[tT];
        if (i == j) s += h[NPAIR + i];
    }
    out[t] = (float)s;
}

extern "C" void kernel_launch(void* const* d_in, const int* in_sizes, int n_in,
                              void* d_out, int out_size, void* d_ws, size_t ws_size,
                              hipStream_t stream) {
    const int* tgt = (const int*)d_in[0];
    float* out = (float*)d_out;
    unsigned int* ws = (unsigned int*)d_ws;

    int nparts = 1;
    while (nparts * 2 <= 32 &&
           (size_t)(nparts * 2) * HSIZE * sizeof(unsigned int) <= ws_size)
        nparts *= 2;

    int zn = nparts * HSIZE;
    zero_kernel<<<(zn + 255) / 256, 256, 0, stream>>>(ws, zn);
    adj_kernel<<<NBLK, 256, 0, stream>>>(tgt, ws, nparts - 1);
    final_kernel<<<(NPAIR + 255) / 256, 256, 0, stream>>>(ws, out, nparts);
}